// Round 1
// baseline (472.210 us; speedup 1.0000x reference)
//
#include <hip/hip_runtime.h>

#define NXg 4096
#define NYg 4096
#define RROWS 8

typedef float v4f __attribute__((ext_vector_type(4)));

__device__ __forceinline__ v4f ldv(const float* p) { return *(const v4f*)p; }

__global__ __launch_bounds__(256) void fdtd_step_kernel(
    const float* __restrict__ ez, const float* __restrict__ hx,
    const float* __restrict__ hy, const float* __restrict__ eps,
    const float* __restrict__ mu, const float* __restrict__ sigma,
    float* __restrict__ ez_out, float* __restrict__ hx_out,
    float* __restrict__ hy_out)
{
    const int j0 = (blockIdx.x * blockDim.x + threadIdx.x) * 4;  // 4 elems/thread
    const int i0 = blockIdx.y * RROWS;                            // first output row

    constexpr float DT = 5e-4f;
    constexpr float inv2dx = 500.0f;   // 1/(2*DX)
    constexpr float inv2dy = 500.0f;   // 1/(2*DY)

    // clamped j-neighbor vector offsets (clamped values only feed masked slots)
    const long jm = (j0 == 0) ? (long)j0 : (long)j0 - 4;
    const long jp = (j0 == NYg - 4) ? (long)j0 : (long)j0 + 4;

    // clamped row byte-base (clamped rows only feed masked lanes)
    auto rowb = [](int r) -> long {
        r = r < 0 ? 0 : (r > NXg - 1 ? NXg - 1 : r);
        return (long)r * NYg;
    };

    // ---- rolling register state (vertical reuse captured in VGPRs) ----
    v4f ezm2 = ldv(ez + rowb(i0 - 2) + j0);
    v4f ezm1 = ldv(ez + rowb(i0 - 1) + j0);
    v4f ezc  = ldv(ez + rowb(i0)     + j0);
    v4f ezp1 = ldv(ez + rowb(i0 + 1) + j0);
    v4f mum1 = ldv(mu + rowb(i0 - 1) + j0);
    v4f muc  = ldv(mu + rowb(i0)     + j0);
    v4f hym1 = ldv(hy + rowb(i0 - 1) + j0);
    v4f hyc  = ldv(hy + rowb(i0)     + j0);

#pragma unroll
    for (int s = 0; s < RROWS; ++s) {
        const int i = i0 + s;
        const long row = (long)i * NYg;
        const long idx = row + j0;

        // new loads this step: 1 ez row, 1 mu row, 1 hy row (no halo needed),
        // j-halos for the center row, and the read-once streams.
        const v4f ezp2 = ldv(ez + rowb(i + 2) + j0);
        const v4f mup1 = ldv(mu + rowb(i + 1) + j0);
        const v4f hyp1 = ldv(hy + rowb(i + 1) + j0);

        const v4f ezL = ldv(ez + row + jm);
        const v4f ezR = ldv(ez + row + jp);
        const v4f muL = ldv(mu + row + jm);
        const v4f muR = ldv(mu + row + jp);
        const v4f hxL = ldv(hx + row + jm);
        const v4f hxC = ldv(hx + idx);
        const v4f hxR = ldv(hx + row + jp);
        const v4f ep4 = __builtin_nontemporal_load((const v4f*)(eps + idx));
        const v4f sg4 = __builtin_nontemporal_load((const v4f*)(sigma + idx));

        const bool iin = (i >= 1) && (i < NXg - 1);
        const bool iP2 = (i < NXg - 2);
        const bool iM2 = (i >= 2);

        // 12-wide windows for j-neighbor access (center elem e is at w[e+4])
        float ezw[12], hxw[12], muw[12];
        *(v4f*)&ezw[0] = ezL; *(v4f*)&ezw[4] = ezc; *(v4f*)&ezw[8] = ezR;
        *(v4f*)&hxw[0] = hxL; *(v4f*)&hxw[4] = hxC; *(v4f*)&hxw[8] = hxR;
        *(v4f*)&muw[0] = muL; *(v4f*)&muw[4] = muc; *(v4f*)&muw[8] = muR;

        v4f ezo, hxo, hyo;

#pragma unroll
        for (int e = 0; e < 4; ++e) {
            const int j = j0 + e;
            const bool jin = (j >= 1) && (j < NYg - 1);
            const bool interior = iin && jin;

            const float ezCv  = ezw[e + 4];
            const float invmu = __builtin_amdgcn_rcpf(muw[e + 4]);

            const float ddy = interior ? (ezw[e + 5] - ezw[e + 3]) * inv2dy : 0.0f;
            const float ddx = interior ? (ezp1[e] - ezm1[e]) * inv2dx : 0.0f;

            const float hx_new = hxw[e + 4] - DT * ddy * invmu;
            const float hy_new = hyc[e]     + DT * ddx * invmu;

            float curl = 0.0f;
            if (interior) {
                const float dExP = iP2 ? (ezp2[e] - ezCv) * inv2dx : 0.0f;
                const float dExM = iM2 ? (ezCv - ezm2[e]) * inv2dx : 0.0f;
                const float hyP = hyp1[e] + DT * dExP * __builtin_amdgcn_rcpf(mup1[e]);
                const float hyM = hym1[e] + DT * dExM * __builtin_amdgcn_rcpf(mum1[e]);

                const float dEyP = (j < NYg - 2) ? (ezw[e + 6] - ezCv) * inv2dy : 0.0f;
                const float dEyM = (j >= 2)      ? (ezCv - ezw[e + 2]) * inv2dy : 0.0f;
                const float hxP = hxw[e + 5] - DT * dEyP * __builtin_amdgcn_rcpf(muw[e + 5]);
                const float hxM = hxw[e + 3] - DT * dEyM * __builtin_amdgcn_rcpf(muw[e + 3]);

                curl = (hyP - hyM) * inv2dx - (hxP - hxM) * inv2dy;
            }

            const float ep  = ep4[e];
            const float rep = __builtin_amdgcn_rcpf(ep);
            const float sv  = sg4[e] * DT * 0.5f * rep;
            const float Ap  = 1.0f + sv;
            const float Am  = 1.0f - sv;
            const float rAp = __builtin_amdgcn_rcpf(Ap);

            ezo[e] = Am * rAp * ezCv + DT * rAp * rep * curl;
            hxo[e] = hx_new;
            hyo[e] = hy_new;
        }

        __builtin_nontemporal_store(ezo, (v4f*)(ez_out + idx));
        __builtin_nontemporal_store(hxo, (v4f*)(hx_out + idx));
        __builtin_nontemporal_store(hyo, (v4f*)(hy_out + idx));

        // roll the vertical windows down one row (pure register renames)
        ezm2 = ezm1; ezm1 = ezc; ezc = ezp1; ezp1 = ezp2;
        mum1 = muc;  muc = mup1;
        hym1 = hyc;  hyc = hyp1;
    }
}

extern "C" void kernel_launch(void* const* d_in, const int* in_sizes, int n_in,
                              void* d_out, int out_size, void* d_ws, size_t ws_size,
                              hipStream_t stream) {
    const float* ez    = (const float*)d_in[0];
    const float* hx    = (const float*)d_in[1];
    const float* hy    = (const float*)d_in[2];
    const float* eps   = (const float*)d_in[3];
    const float* mu    = (const float*)d_in[4];
    const float* sigma = (const float*)d_in[5];

    const long N = (long)NXg * NYg;
    float* out    = (float*)d_out;
    float* ez_out = out;
    float* hx_out = out + N;
    float* hy_out = out + 2 * N;

    dim3 block(256, 1, 1);
    dim3 grid(NYg / (256 * 4), NXg / RROWS, 1);
    fdtd_step_kernel<<<grid, block, 0, stream>>>(ez, hx, hy, eps, mu, sigma,
                                                 ez_out, hx_out, hy_out);
}